// Round 3
// baseline (1261.660 us; speedup 1.0000x reference)
//
#include <hip/hip_runtime.h>
#include <hip/hip_bf16.h>

// Shapes (fixed by the problem)
#define VV 50000
#define EE 128
#define HH 128
#define OO 128
#define BB 64
#define TT 512

typedef __bf16 bf16_t;
typedef __attribute__((ext_vector_type(8))) __bf16 bf16x8;
typedef __attribute__((ext_vector_type(4))) __bf16 bf16x4;
typedef __attribute__((ext_vector_type(4))) float floatx4;

__device__ __forceinline__ bf16x8 ldb8(const bf16_t* p) {
    return *reinterpret_cast<const bf16x8*>(p);
}

// load 8 consecutive fp32, round to bf16 fragment (two float4 loads, 16B-aligned)
__device__ __forceinline__ bf16x8 ldf8_bf(const float* p) {
    const float4* q = reinterpret_cast<const float4*>(p);
    float4 u = q[0], v = q[1];
    bf16x8 r;
    r[0] = (__bf16)u.x; r[1] = (__bf16)u.y; r[2] = (__bf16)u.z; r[3] = (__bf16)u.w;
    r[4] = (__bf16)v.x; r[5] = (__bf16)v.y; r[6] = (__bf16)v.z; r[7] = (__bf16)v.w;
    return r;
}

__device__ __forceinline__ float sigmoid_f(float x) {
    return 1.0f / (1.0f + __expf(-x));
}
__device__ __forceinline__ float tanh_f(float x) {
    float e = __expf(2.0f * x);
    return 1.0f - 2.0f / (e + 1.0f);
}

// LDS-only barrier: wait LDS ops, sync — do NOT drain vmcnt (global stores/
// prefetch loads stay in flight across steps; __syncthreads would force
// s_waitcnt vmcnt(0) = ~2000 cyc/step of L2 round-trips on the critical path).
__device__ __forceinline__ void lds_barrier() {
    asm volatile("s_waitcnt lgkmcnt(0)\n\ts_barrier" ::: "memory");
}

// -------- K1: xh[r][n] = emb[X[r]] @ W_e2i^T + b_e2i   (r = b*T + t, 32768 rows)
__global__ __launch_bounds__(256) void k1_xh(const int* __restrict__ X,
                                             const float* __restrict__ emb,
                                             const float* __restrict__ We,
                                             const float* __restrict__ be,
                                             bf16_t* __restrict__ xh) {
    int r0 = blockIdx.x * 16;
    int lane = threadIdx.x & 63;
    int w2 = threadIdx.x >> 6;       // wave 0..3
    int quad = lane >> 4, col = lane & 15;

    int v = X[r0 + col];             // A row m = lane&15
    bf16x8 a[4];
#pragma unroll
    for (int kc = 0; kc < 4; ++kc)
        a[kc] = ldf8_bf(emb + (size_t)v * EE + kc * 32 + quad * 8);

#pragma unroll
    for (int tl = 0; tl < 2; ++tl) {
        int n = 32 * w2 + 16 * tl + col;     // B row n = lane&15
        floatx4 acc = {0.f, 0.f, 0.f, 0.f};
#pragma unroll
        for (int kc = 0; kc < 4; ++kc) {
            bf16x8 bw = ldf8_bf(We + (size_t)n * EE + kc * 32 + quad * 8);
            acc = __builtin_amdgcn_mfma_f32_16x16x32_bf16(a[kc], bw, acc, 0, 0, 0);
        }
        float bias = be[n];
#pragma unroll
        for (int r = 0; r < 4; ++r) {
            int row = quad * 4 + r;          // C/D row
            xh[(size_t)(r0 + row) * HH + n] = (bf16_t)(acc[r] + bias);
        }
    }
}

// -------- K2: gx2[dir][t][n=gate*128+j][b] = xh @ Wih^T + bih  (bf16 scratch, b-innermost)
// tile = (t, group of 16 b). D rows (quad*4+r) = 4 consecutive b -> one 8B store.
__global__ __launch_bounds__(256) void k2_gx(const bf16_t* __restrict__ xh,
                                             const float* __restrict__ Wf,
                                             const float* __restrict__ bf_,
                                             const float* __restrict__ Wb,
                                             const float* __restrict__ bb_,
                                             bf16_t* __restrict__ gx2) {
    int dir = blockIdx.y;
    const float* W = dir ? Wb : Wf;
    const float* bi = dir ? bb_ : bf_;
    int tile = blockIdx.x;           // 0..2047
    int t = tile >> 2;
    int b0 = (tile & 3) * 16;
    int lane = threadIdx.x & 63;
    int w2 = threadIdx.x >> 6;
    int quad = lane >> 4, col = lane & 15;

    // A rows = samples b0+col at time t ; xh row index r = b*T + t
    bf16x8 a[4];
#pragma unroll
    for (int kc = 0; kc < 4; ++kc)
        a[kc] = ldb8(xh + ((size_t)(b0 + col) * TT + t) * HH + kc * 32 + quad * 8);

    size_t tb = ((size_t)dir * TT + t) * 384;

#pragma unroll
    for (int tl = 0; tl < 6; ++tl) {
        int n = 16 * (w2 * 6 + tl) + col;    // 0..383
        floatx4 acc = {0.f, 0.f, 0.f, 0.f};
#pragma unroll
        for (int kc = 0; kc < 4; ++kc) {
            bf16x8 bw = ldf8_bf(W + (size_t)n * HH + kc * 32 + quad * 8);
            acc = __builtin_amdgcn_mfma_f32_16x16x32_bf16(a[kc], bw, acc, 0, 0, 0);
        }
        float bias = bi[n];
        bf16x4 pack;
#pragma unroll
        for (int r = 0; r < 4; ++r)
            pack[r] = (__bf16)(acc[r] + bias);   // D row r -> b = b0 + quad*4 + r
        *reinterpret_cast<bf16x4*>(gx2 + (tb + n) * BB + b0 + quad * 4) = pack;
    }
}

// -------- K3: masked GRU recurrence, both directions.
// grid (4 groups of 16 samples, 2 dirs), 512 threads = 8 waves.
// Wave w owns gate columns j = 16w+col for all three gates: r/z/n for the same
// (sample, j) land in the same lane+reg -> in-register gate math.
// Double-buffered LDS h + lgkm-only barrier: ONE barrier/step, no vmcnt drain.
#define HPAD 136
#define HBUF (16 * HPAD)
__global__ __launch_bounds__(512) void k3_gru(const bf16_t* __restrict__ gx2,
                                              const float* __restrict__ Whh_f,
                                              const float* __restrict__ bhh_f,
                                              const float* __restrict__ Whh_b,
                                              const float* __restrict__ bhh_b,
                                              const int* __restrict__ lens,
                                              bf16_t* __restrict__ hist) {
    int g = blockIdx.x;      // sample group: samples 16g..16g+15
    int dir = blockIdx.y;
    const float* Whh = dir ? Whh_b : Whh_f;
    const float* bhh = dir ? bhh_b : bhh_f;

    int tid = threadIdx.x;
    int w = tid >> 6;        // wave 0..7
    int lane = tid & 63;
    int quad = lane >> 4, col = lane & 15;
    int j = 16 * w + col;    // owned hidden column

    __shared__ bf16_t hl[2 * HBUF];   // double-buffered h, padded rows
    for (int i = tid; i < 2 * HBUF; i += 512) hl[i] = (bf16_t)0.f;

    int bloc[4], len4[4];
    float h[4] = {0.f, 0.f, 0.f, 0.f};
#pragma unroll
    for (int r = 0; r < 4; ++r) {
        bloc[r] = quad * 4 + r;
        len4[r] = lens[16 * g + bloc[r]];
    }
    // group max length (lens sorted descending, but compute robustly)
    int Lmax = 0;
    for (int i = 0; i < 16; ++i) Lmax = max(Lmax, lens[16 * g + i]);

    float bhr = bhh[j];
    float bhz = bhh[128 + j];
    float bhn = bhh[256 + j];

    // Whh B-fragments (bf16-rounded), resident for all steps
    bf16x8 Bw[3][4];
#pragma unroll
    for (int gate = 0; gate < 3; ++gate)
#pragma unroll
        for (int kc = 0; kc < 4; ++kc)
            Bw[gate][kc] = ldf8_bf(Whh + (size_t)(gate * 128 + j) * HH + kc * 32 + quad * 8);

    size_t dbase = (size_t)dir * TT;
    int bbase = 16 * g + quad * 4;   // 4 consecutive samples per lane

    // preload gx for first step: one 8B load per gate (4 consecutive b)
    float gxc[3][4];
    {
        int t0 = dir ? (Lmax - 1) : 0;
#pragma unroll
        for (int gate = 0; gate < 3; ++gate) {
            bf16x4 v = *reinterpret_cast<const bf16x4*>(
                gx2 + ((dbase + t0) * 384 + gate * 128 + j) * BB + bbase);
#pragma unroll
            for (int r = 0; r < 4; ++r) gxc[gate][r] = (float)v[r];
        }
    }
    lds_barrier();   // zero-init visible

    for (int s = 0; s < Lmax; ++s) {
        int t = dir ? (Lmax - 1 - s) : s;
        const bf16_t* hc = hl + (s & 1) * HBUF;
        bf16_t* hn = hl + ((s + 1) & 1) * HBUF;

        // A fragments from LDS h  (A row m = lane&15 = col)
        bf16x8 a[4];
#pragma unroll
        for (int kc = 0; kc < 4; ++kc)
            a[kc] = ldb8(hc + col * HPAD + kc * 32 + quad * 8);

        // 2 accumulator chains per gate for MFMA ILP
        floatx4 ar0 = {0,0,0,0}, ar1 = {0,0,0,0};
        floatx4 az0 = {0,0,0,0}, az1 = {0,0,0,0};
        floatx4 an0 = {0,0,0,0}, an1 = {0,0,0,0};
        ar0 = __builtin_amdgcn_mfma_f32_16x16x32_bf16(a[0], Bw[0][0], ar0, 0, 0, 0);
        az0 = __builtin_amdgcn_mfma_f32_16x16x32_bf16(a[0], Bw[1][0], az0, 0, 0, 0);
        an0 = __builtin_amdgcn_mfma_f32_16x16x32_bf16(a[0], Bw[2][0], an0, 0, 0, 0);
        ar1 = __builtin_amdgcn_mfma_f32_16x16x32_bf16(a[2], Bw[0][2], ar1, 0, 0, 0);
        az1 = __builtin_amdgcn_mfma_f32_16x16x32_bf16(a[2], Bw[1][2], az1, 0, 0, 0);
        an1 = __builtin_amdgcn_mfma_f32_16x16x32_bf16(a[2], Bw[2][2], an1, 0, 0, 0);
        ar0 = __builtin_amdgcn_mfma_f32_16x16x32_bf16(a[1], Bw[0][1], ar0, 0, 0, 0);
        az0 = __builtin_amdgcn_mfma_f32_16x16x32_bf16(a[1], Bw[1][1], az0, 0, 0, 0);
        an0 = __builtin_amdgcn_mfma_f32_16x16x32_bf16(a[1], Bw[2][1], an0, 0, 0, 0);
        ar1 = __builtin_amdgcn_mfma_f32_16x16x32_bf16(a[3], Bw[0][3], ar1, 0, 0, 0);
        az1 = __builtin_amdgcn_mfma_f32_16x16x32_bf16(a[3], Bw[1][3], az1, 0, 0, 0);
        an1 = __builtin_amdgcn_mfma_f32_16x16x32_bf16(a[3], Bw[2][3], an1, 0, 0, 0);

        // prefetch next step's gx (3 x 8B; in flight until next iteration)
        float gxn_[3][4] = {{0,0,0,0},{0,0,0,0},{0,0,0,0}};
        if (s < Lmax - 1) {
            int tn = dir ? (Lmax - 2 - s) : (s + 1);
#pragma unroll
            for (int gate = 0; gate < 3; ++gate) {
                bf16x4 v = *reinterpret_cast<const bf16x4*>(
                    gx2 + ((dbase + tn) * 384 + gate * 128 + j) * BB + bbase);
#pragma unroll
                for (int r = 0; r < 4; ++r) gxn_[gate][r] = (float)v[r];
            }
        }

        // gates + state update (D row = quad*4+reg = local sample, D col = j)
#pragma unroll
        for (int r = 0; r < 4; ++r) {
            float rg = sigmoid_f(gxc[0][r] + ar0[r] + ar1[r] + bhr);
            float zg = sigmoid_f(gxc[1][r] + az0[r] + az1[r] + bhz);
            float ng = tanh_f(gxc[2][r] + rg * (an0[r] + an1[r] + bhn));
            float hn_ = ng + zg * (h[r] - ng);
            h[r] = (t < len4[r]) ? hn_ : h[r];
            hn[bloc[r] * HPAD + j] = (bf16_t)h[r];
            hist[((dbase + t) * BB + 16 * g + bloc[r]) * HH + j] = (bf16_t)h[r];
        }

        lds_barrier();   // new h visible; old buffer free (reads done pre-barrier)

#pragma unroll
        for (int gate = 0; gate < 3; ++gate)
#pragma unroll
            for (int r = 0; r < 4; ++r)
                gxc[gate][r] = gxn_[gate][r];
    }
}

// -------- K4: Y = tanh(Hout @ W_h2o^T + b), score = sum(Y*u_w) ; scores[b][t] fp32
__global__ __launch_bounds__(256) void k4_scores(const bf16_t* __restrict__ hist,
                                                 const float* __restrict__ Wh2o,
                                                 const float* __restrict__ bh2o,
                                                 const float* __restrict__ uw,
                                                 float* __restrict__ scores) {
    int tile = blockIdx.x;          // rows r = t*64 + b
    int r0 = tile * 16;
    int t = r0 >> 6;
    int b0 = r0 & 63;
    int lane = threadIdx.x & 63;
    int w2 = threadIdx.x >> 6;
    int quad = lane >> 4, col = lane & 15;

    // A fragments: Hout row (b0+col), K=256 split: kc 0..3 from h_f, 4..7 from h_b
    bf16x8 a[8];
    int brow = b0 + col;
#pragma unroll
    for (int kc = 0; kc < 8; ++kc) {
        int dir = kc >> 2;
        int k0 = (kc & 3) * 32;
        a[kc] = ldb8(hist + (((size_t)dir * TT + t) * BB + brow) * HH + k0 + quad * 8);
    }

    float p4[4] = {0.f, 0.f, 0.f, 0.f};
#pragma unroll
    for (int tl = 0; tl < 2; ++tl) {
        int n = 32 * w2 + 16 * tl + col;
        floatx4 acc = {0.f, 0.f, 0.f, 0.f};
#pragma unroll
        for (int kc = 0; kc < 8; ++kc) {
            bf16x8 bw = ldf8_bf(Wh2o + (size_t)n * 256 + kc * 32 + quad * 8);
            acc = __builtin_amdgcn_mfma_f32_16x16x32_bf16(a[kc], bw, acc, 0, 0, 0);
        }
        float bias = bh2o[n];
        float u = uw[n];
#pragma unroll
        for (int r = 0; r < 4; ++r) {
            float y = tanh_f(acc[r] + bias);
            p4[r] += y * u;
        }
    }
    // reduce over the 16 cols of this quad group (rows = quad*4+r identical across them)
#pragma unroll
    for (int m = 1; m < 16; m <<= 1)
#pragma unroll
        for (int r = 0; r < 4; ++r)
            p4[r] += __shfl_xor(p4[r], m, 64);

    __shared__ float part[16][4];
    if (col == 0) {
#pragma unroll
        for (int r = 0; r < 4; ++r) part[quad * 4 + r][w2] = p4[r];
    }
    __syncthreads();
    if (threadIdx.x < 16) {
        float s = part[threadIdx.x][0] + part[threadIdx.x][1] +
                  part[threadIdx.x][2] + part[threadIdx.x][3];
        scores[(size_t)(b0 + threadIdx.x) * TT + t] = s;
    }
}

// -------- K5: per-sample softmax over valid t + pooled = sum_t alpha[t]*Hout[b][t][:]
__global__ __launch_bounds__(256) void k5_pool(const float* __restrict__ scores,
                                               const bf16_t* __restrict__ hist,
                                               const int* __restrict__ lens,
                                               float* __restrict__ out) {
    int b = blockIdx.x;
    int tid = threadIdx.x;
    int len = lens[b];
    __shared__ float alpha[TT];
    __shared__ float red[256];
    const float* srow = scores + (size_t)b * TT;

    float m = -1e30f;
    for (int t = tid; t < len; t += 256) m = fmaxf(m, srow[t]);
    red[tid] = m;
    __syncthreads();
    for (int s = 128; s > 0; s >>= 1) {
        if (tid < s) red[tid] = fmaxf(red[tid], red[tid + s]);
        __syncthreads();
    }
    float mx = red[0];
    __syncthreads();

    float sum = 0.f;
    for (int t = tid; t < TT; t += 256) {
        float e = (t < len) ? __expf(srow[t] - mx) : 0.f;
        alpha[t] = e;
        sum += e;
    }
    red[tid] = sum;
    __syncthreads();
    for (int s = 128; s > 0; s >>= 1) {
        if (tid < s) red[tid] += red[tid + s];
        __syncthreads();
    }
    float inv = 1.0f / red[0];
    __syncthreads();

    int c = tid;                 // 0..255 output channel
    int dir = c >> 7;
    int j = c & 127;
    const bf16_t* hbase = hist + ((size_t)dir * TT * BB + b) * HH + j;
    float acc = 0.f;
    int t = 0;
    for (; t + 4 <= len; t += 4) {
        acc += alpha[t + 0] * (float)hbase[(size_t)(t + 0) * BB * HH];
        acc += alpha[t + 1] * (float)hbase[(size_t)(t + 1) * BB * HH];
        acc += alpha[t + 2] * (float)hbase[(size_t)(t + 2) * BB * HH];
        acc += alpha[t + 3] * (float)hbase[(size_t)(t + 3) * BB * HH];
    }
    for (; t < len; ++t) acc += alpha[t] * (float)hbase[(size_t)t * BB * HH];

    out[(size_t)b * 256 + c] = acc * inv;
}

extern "C" void kernel_launch(void* const* d_in, const int* in_sizes, int n_in,
                              void* d_out, int out_size, void* d_ws, size_t ws_size,
                              hipStream_t stream) {
    const int* X       = (const int*)d_in[0];
    const int* lens    = (const int*)d_in[1];
    const float* emb   = (const float*)d_in[3];
    const float* We2i  = (const float*)d_in[4];
    const float* be2i  = (const float*)d_in[5];
    const float* Wihf  = (const float*)d_in[6];
    const float* Whhf  = (const float*)d_in[7];
    const float* bihf  = (const float*)d_in[8];
    const float* bhhf  = (const float*)d_in[9];
    const float* Wihb  = (const float*)d_in[10];
    const float* Whhb  = (const float*)d_in[11];
    const float* bihb  = (const float*)d_in[12];
    const float* bhhb  = (const float*)d_in[13];
    const float* Wh2o  = (const float*)d_in[14];
    const float* bh2o  = (const float*)d_in[15];
    const float* uw    = (const float*)d_in[16];

    char* ws = (char*)d_ws;
    size_t off = 0;
    bf16_t* xh = (bf16_t*)(ws + off);   off += (size_t)BB * TT * HH * 2;            // 8.4 MB
    bf16_t* gx2 = (bf16_t*)(ws + off);  off += (size_t)2 * TT * 384 * BB * 2;       // 50.3 MB
    bf16_t* hist = (bf16_t*)(ws + off); off += (size_t)2 * TT * BB * HH * 2;        // 16.8 MB
    float* scores = (float*)(ws + off); off += (size_t)BB * TT * 4;                 // 0.13 MB

    float* out = (float*)d_out;

    k1_xh<<<dim3(BB * TT / 16), dim3(256), 0, stream>>>(X, emb, We2i, be2i, xh);
    k2_gx<<<dim3(TT * 4, 2), dim3(256), 0, stream>>>(xh, Wihf, bihf, Wihb, bihb, gx2);
    k3_gru<<<dim3(4, 2), dim3(512), 0, stream>>>(gx2, Whhf, bhhf, Whhb, bhhb, lens, hist);
    k4_scores<<<dim3(BB * TT / 16), dim3(256), 0, stream>>>(hist, Wh2o, bh2o, uw, scores);
    k5_pool<<<dim3(BB), dim3(256), 0, stream>>>(scores, hist, lens, out);
}

// Round 4
// 870.114 us; speedup vs baseline: 1.4500x; 1.4500x over previous
//
#include <hip/hip_runtime.h>
#include <hip/hip_bf16.h>

// Shapes (fixed by the problem)
#define VV 50000
#define EE 128
#define HH 128
#define OO 128
#define BB 64
#define TT 512

typedef __bf16 bf16_t;
typedef __attribute__((ext_vector_type(8))) __bf16 bf16x8;
typedef __attribute__((ext_vector_type(4))) __bf16 bf16x4;
typedef __attribute__((ext_vector_type(4))) float floatx4;

__device__ __forceinline__ bf16x8 ldb8(const bf16_t* p) {
    return *reinterpret_cast<const bf16x8*>(p);
}

// load 8 consecutive fp32, round to bf16 fragment (two float4 loads, 16B-aligned)
__device__ __forceinline__ bf16x8 ldf8_bf(const float* p) {
    const float4* q = reinterpret_cast<const float4*>(p);
    float4 u = q[0], v = q[1];
    bf16x8 r;
    r[0] = (__bf16)u.x; r[1] = (__bf16)u.y; r[2] = (__bf16)u.z; r[3] = (__bf16)u.w;
    r[4] = (__bf16)v.x; r[5] = (__bf16)v.y; r[6] = (__bf16)v.z; r[7] = (__bf16)v.w;
    return r;
}

__device__ __forceinline__ float sigmoid_f(float x) {
    return 1.0f / (1.0f + __expf(-x));
}
__device__ __forceinline__ float tanh_f(float x) {
    float e = __expf(2.0f * x);
    return 1.0f - 2.0f / (e + 1.0f);
}

// LDS-only barrier: wait LDS ops, sync — do NOT drain vmcnt (hist stores and
// gx ring-prefetch loads stay in flight across steps).
__device__ __forceinline__ void lds_barrier() {
    asm volatile("s_waitcnt lgkmcnt(0)\n\ts_barrier" ::: "memory");
}

// -------- K1: xh[r][n] = emb[X[r]] @ W_e2i^T + b_e2i   (r = b*T + t, 32768 rows)
__global__ __launch_bounds__(256) void k1_xh(const int* __restrict__ X,
                                             const float* __restrict__ emb,
                                             const float* __restrict__ We,
                                             const float* __restrict__ be,
                                             bf16_t* __restrict__ xh) {
    int r0 = blockIdx.x * 16;
    int lane = threadIdx.x & 63;
    int w2 = threadIdx.x >> 6;       // wave 0..3
    int quad = lane >> 4, col = lane & 15;

    int v = X[r0 + col];             // A row m = lane&15
    bf16x8 a[4];
#pragma unroll
    for (int kc = 0; kc < 4; ++kc)
        a[kc] = ldf8_bf(emb + (size_t)v * EE + kc * 32 + quad * 8);

#pragma unroll
    for (int tl = 0; tl < 2; ++tl) {
        int n = 32 * w2 + 16 * tl + col;     // B row n = lane&15
        floatx4 acc = {0.f, 0.f, 0.f, 0.f};
#pragma unroll
        for (int kc = 0; kc < 4; ++kc) {
            bf16x8 bw = ldf8_bf(We + (size_t)n * EE + kc * 32 + quad * 8);
            acc = __builtin_amdgcn_mfma_f32_16x16x32_bf16(a[kc], bw, acc, 0, 0, 0);
        }
        float bias = be[n];
#pragma unroll
        for (int r = 0; r < 4; ++r) {
            int row = quad * 4 + r;          // C/D row
            xh[(size_t)(r0 + row) * HH + n] = (bf16_t)(acc[r] + bias);
        }
    }
}

// -------- K2: gx3[dir][g][t][n][b16] = xh @ Wih^T + bih  (bf16 scratch)
// Layout is per-(dir, sample-group) contiguous so each K3 block reads its own
// 12 KB/step region: no cross-XCD cache-line sharing (R3's 4x over-fetch bug).
__global__ __launch_bounds__(256) void k2_gx(const bf16_t* __restrict__ xh,
                                             const float* __restrict__ Wf,
                                             const float* __restrict__ bf_,
                                             const float* __restrict__ Wb,
                                             const float* __restrict__ bb_,
                                             bf16_t* __restrict__ gx3) {
    int dir = blockIdx.y;
    const float* W = dir ? Wb : Wf;
    const float* bi = dir ? bb_ : bf_;
    int tile = blockIdx.x;           // 0..2047
    int t = tile >> 2;
    int g = tile & 3;
    int b0 = g * 16;
    int lane = threadIdx.x & 63;
    int w2 = threadIdx.x >> 6;
    int quad = lane >> 4, col = lane & 15;

    // A rows = samples b0+col at time t ; xh row index r = b*T + t
    bf16x8 a[4];
#pragma unroll
    for (int kc = 0; kc < 4; ++kc)
        a[kc] = ldb8(xh + ((size_t)(b0 + col) * TT + t) * HH + kc * 32 + quad * 8);

    size_t tb = ((size_t)(dir * 4 + g) * TT + t) * 384;

#pragma unroll
    for (int tl = 0; tl < 6; ++tl) {
        int n = 16 * (w2 * 6 + tl) + col;    // 0..383
        floatx4 acc = {0.f, 0.f, 0.f, 0.f};
#pragma unroll
        for (int kc = 0; kc < 4; ++kc) {
            bf16x8 bw = ldf8_bf(W + (size_t)n * HH + kc * 32 + quad * 8);
            acc = __builtin_amdgcn_mfma_f32_16x16x32_bf16(a[kc], bw, acc, 0, 0, 0);
        }
        float bias = bi[n];
        bf16x4 pack;
#pragma unroll
        for (int r = 0; r < 4; ++r)
            pack[r] = (__bf16)(acc[r] + bias);   // D row r -> local sample quad*4+r
        *reinterpret_cast<bf16x4*>(gx3 + (tb + n) * 16 + quad * 4) = pack;
    }
}

// -------- K3: masked GRU recurrence, both directions.
// grid (4 groups of 16 samples, 2 dirs), 512 threads = 8 waves.
// Wave w owns gate columns j = 16w+col for all three gates: r/z/n for the same
// (sample, j) land in the same lane+reg -> in-register gate math.
// Depth-4 register ring prefetch of gx (latency ~900cyc amortized over 4 steps),
// double-buffered LDS h, single lgkm-only barrier per step.
#define HPAD 136
#define HBUF (16 * HPAD)
__global__ __launch_bounds__(512) void k3_gru(const bf16_t* __restrict__ gx3,
                                              const float* __restrict__ Whh_f,
                                              const float* __restrict__ bhh_f,
                                              const float* __restrict__ Whh_b,
                                              const float* __restrict__ bhh_b,
                                              const int* __restrict__ lens,
                                              bf16_t* __restrict__ hist) {
    int g = blockIdx.x;      // sample group: samples 16g..16g+15
    int dir = blockIdx.y;
    const float* Whh = dir ? Whh_b : Whh_f;
    const float* bhh = dir ? bhh_b : bhh_f;

    int tid = threadIdx.x;
    int w = tid >> 6;        // wave 0..7
    int lane = tid & 63;
    int quad = lane >> 4, col = lane & 15;
    int j = 16 * w + col;    // owned hidden column

    __shared__ bf16_t hl[2 * HBUF];   // double-buffered h, padded rows
    for (int i = tid; i < 2 * HBUF; i += 512) hl[i] = (bf16_t)0.f;

    int bloc[4], len4[4];
    float h[4] = {0.f, 0.f, 0.f, 0.f};
#pragma unroll
    for (int r = 0; r < 4; ++r) {
        bloc[r] = quad * 4 + r;
        len4[r] = lens[16 * g + bloc[r]];
    }
    // group max length (lens sorted descending, but compute robustly)
    int Lmax = 0;
    for (int i = 0; i < 16; ++i) Lmax = max(Lmax, lens[16 * g + i]);

    float bhr = bhh[j];
    float bhz = bhh[128 + j];
    float bhn = bhh[256 + j];

    // Whh B-fragments (bf16-rounded), resident for all steps
    bf16x8 Bw[3][4];
#pragma unroll
    for (int gate = 0; gate < 3; ++gate)
#pragma unroll
        for (int kc = 0; kc < 4; ++kc)
            Bw[gate][kc] = ldf8_bf(Whh + (size_t)(gate * 128 + j) * HH + kc * 32 + quad * 8);

    // per-block contiguous gx region; per-lane offsets
    const bf16_t* gbase = gx3 + (size_t)(dir * 4 + g) * TT * 6144;
    int loff[3];
#pragma unroll
    for (int gate = 0; gate < 3; ++gate)
        loff[gate] = (gate * 128 + j) * 16 + quad * 4;

    size_t dbase = (size_t)dir * TT;
    int S4 = (Lmax + 3) & ~3;

    // prefetch ring, depth 4 (raw bf16; convert at consumption)
    bf16x4 ring[4][3];
#pragma unroll
    for (int u = 0; u < 4; ++u) {
        int tr = dir ? (Lmax - 1 - u) : u;
        int t = min(max(tr, 0), Lmax - 1);
#pragma unroll
        for (int gate = 0; gate < 3; ++gate)
            ring[u][gate] = *reinterpret_cast<const bf16x4*>(gbase + (size_t)t * 6144 + loff[gate]);
    }
    lds_barrier();   // zero-init visible

    for (int sb = 0; sb < S4; sb += 4) {
#pragma unroll
        for (int u = 0; u < 4; ++u) {
            int s = sb + u;
            int tr = dir ? (Lmax - 1 - s) : s;
            int t = min(max(tr, 0), Lmax - 1);     // clamped for tail steps
            const bf16_t* hc = hl + (s & 1) * HBUF;
            bf16_t* hn = hl + ((s + 1) & 1) * HBUF;

            // consume ring slot u (loads issued 4 steps ago -> long retired)
            float gxc[3][4];
#pragma unroll
            for (int gate = 0; gate < 3; ++gate)
#pragma unroll
                for (int r = 0; r < 4; ++r)
                    gxc[gate][r] = (float)ring[u][gate][r];

            // A fragments from LDS h  (A row m = lane&15 = col)
            bf16x8 a[4];
#pragma unroll
            for (int kc = 0; kc < 4; ++kc)
                a[kc] = ldb8(hc + col * HPAD + kc * 32 + quad * 8);

            // 2 accumulator chains per gate for MFMA ILP
            floatx4 ar0 = {0,0,0,0}, ar1 = {0,0,0,0};
            floatx4 az0 = {0,0,0,0}, az1 = {0,0,0,0};
            floatx4 an0 = {0,0,0,0}, an1 = {0,0,0,0};
            ar0 = __builtin_amdgcn_mfma_f32_16x16x32_bf16(a[0], Bw[0][0], ar0, 0, 0, 0);
            az0 = __builtin_amdgcn_mfma_f32_16x16x32_bf16(a[0], Bw[1][0], az0, 0, 0, 0);
            an0 = __builtin_amdgcn_mfma_f32_16x16x32_bf16(a[0], Bw[2][0], an0, 0, 0, 0);
            ar1 = __builtin_amdgcn_mfma_f32_16x16x32_bf16(a[2], Bw[0][2], ar1, 0, 0, 0);
            az1 = __builtin_amdgcn_mfma_f32_16x16x32_bf16(a[2], Bw[1][2], az1, 0, 0, 0);
            an1 = __builtin_amdgcn_mfma_f32_16x16x32_bf16(a[2], Bw[2][2], an1, 0, 0, 0);
            ar0 = __builtin_amdgcn_mfma_f32_16x16x32_bf16(a[1], Bw[0][1], ar0, 0, 0, 0);
            az0 = __builtin_amdgcn_mfma_f32_16x16x32_bf16(a[1], Bw[1][1], az0, 0, 0, 0);
            an0 = __builtin_amdgcn_mfma_f32_16x16x32_bf16(a[1], Bw[2][1], an0, 0, 0, 0);
            ar1 = __builtin_amdgcn_mfma_f32_16x16x32_bf16(a[3], Bw[0][3], ar1, 0, 0, 0);
            az1 = __builtin_amdgcn_mfma_f32_16x16x32_bf16(a[3], Bw[1][3], az1, 0, 0, 0);
            an1 = __builtin_amdgcn_mfma_f32_16x16x32_bf16(a[3], Bw[2][3], an1, 0, 0, 0);

            // refill ring slot u for step s+4 (in flight for 4 steps)
            {
                int sn = s + 4;
                int trn = dir ? (Lmax - 1 - sn) : sn;
                int tn = min(max(trn, 0), Lmax - 1);
#pragma unroll
                for (int gate = 0; gate < 3; ++gate)
                    ring[u][gate] = *reinterpret_cast<const bf16x4*>(gbase + (size_t)tn * 6144 + loff[gate]);
            }

            // gates + state update (D row = quad*4+reg = local sample, D col = j)
            bool live = (s < Lmax);
#pragma unroll
            for (int r = 0; r < 4; ++r) {
                float rg = sigmoid_f(gxc[0][r] + ar0[r] + ar1[r] + bhr);
                float zg = sigmoid_f(gxc[1][r] + az0[r] + az1[r] + bhz);
                float ng = tanh_f(gxc[2][r] + rg * (an0[r] + an1[r] + bhn));
                float hn_ = ng + zg * (h[r] - ng);
                h[r] = (live && (t < len4[r])) ? hn_ : h[r];
                hn[bloc[r] * HPAD + j] = (bf16_t)h[r];
                hist[((dbase + t) * BB + 16 * g + bloc[r]) * HH + j] = (bf16_t)h[r];
            }

            lds_barrier();   // new h visible; old buffer free
        }
    }
}

// -------- K4: Y = tanh(Hout @ W_h2o^T + b), score = sum(Y*u_w) ; scores[b][t] fp32
__global__ __launch_bounds__(256) void k4_scores(const bf16_t* __restrict__ hist,
                                                 const float* __restrict__ Wh2o,
                                                 const float* __restrict__ bh2o,
                                                 const float* __restrict__ uw,
                                                 float* __restrict__ scores) {
    int tile = blockIdx.x;          // rows r = t*64 + b
    int r0 = tile * 16;
    int t = r0 >> 6;
    int b0 = r0 & 63;
    int lane = threadIdx.x & 63;
    int w2 = threadIdx.x >> 6;
    int quad = lane >> 4, col = lane & 15;

    // A fragments: Hout row (b0+col), K=256 split: kc 0..3 from h_f, 4..7 from h_b
    bf16x8 a[8];
    int brow = b0 + col;
#pragma unroll
    for (int kc = 0; kc < 8; ++kc) {
        int dir = kc >> 2;
        int k0 = (kc & 3) * 32;
        a[kc] = ldb8(hist + (((size_t)dir * TT + t) * BB + brow) * HH + k0 + quad * 8);
    }

    float p4[4] = {0.f, 0.f, 0.f, 0.f};
#pragma unroll
    for (int tl = 0; tl < 2; ++tl) {
        int n = 32 * w2 + 16 * tl + col;
        floatx4 acc = {0.f, 0.f, 0.f, 0.f};
#pragma unroll
        for (int kc = 0; kc < 8; ++kc) {
            bf16x8 bw = ldf8_bf(Wh2o + (size_t)n * 256 + kc * 32 + quad * 8);
            acc = __builtin_amdgcn_mfma_f32_16x16x32_bf16(a[kc], bw, acc, 0, 0, 0);
        }
        float bias = bh2o[n];
        float u = uw[n];
#pragma unroll
        for (int r = 0; r < 4; ++r) {
            float y = tanh_f(acc[r] + bias);
            p4[r] += y * u;
        }
    }
    // reduce over the 16 cols of this quad group (rows = quad*4+r identical across them)
#pragma unroll
    for (int m = 1; m < 16; m <<= 1)
#pragma unroll
        for (int r = 0; r < 4; ++r)
            p4[r] += __shfl_xor(p4[r], m, 64);

    __shared__ float part[16][4];
    if (col == 0) {
#pragma unroll
        for (int r = 0; r < 4; ++r) part[quad * 4 + r][w2] = p4[r];
    }
    __syncthreads();
    if (threadIdx.x < 16) {
        float s = part[threadIdx.x][0] + part[threadIdx.x][1] +
                  part[threadIdx.x][2] + part[threadIdx.x][3];
        scores[(size_t)(b0 + threadIdx.x) * TT + t] = s;
    }
}

// -------- K5: per-sample softmax over valid t + pooled = sum_t alpha[t]*Hout[b][t][:]
__global__ __launch_bounds__(256) void k5_pool(const float* __restrict__ scores,
                                               const bf16_t* __restrict__ hist,
                                               const int* __restrict__ lens,
                                               float* __restrict__ out) {
    int b = blockIdx.x;
    int tid = threadIdx.x;
    int len = lens[b];
    __shared__ float alpha[TT];
    __shared__ float red[256];
    const float* srow = scores + (size_t)b * TT;

    float m = -1e30f;
    for (int t = tid; t < len; t += 256) m = fmaxf(m, srow[t]);
    red[tid] = m;
    __syncthreads();
    for (int s = 128; s > 0; s >>= 1) {
        if (tid < s) red[tid] = fmaxf(red[tid], red[tid + s]);
        __syncthreads();
    }
    float mx = red[0];
    __syncthreads();

    float sum = 0.f;
    for (int t = tid; t < TT; t += 256) {
        float e = (t < len) ? __expf(srow[t] - mx) : 0.f;
        alpha[t] = e;
        sum += e;
    }
    red[tid] = sum;
    __syncthreads();
    for (int s = 128; s > 0; s >>= 1) {
        if (tid < s) red[tid] += red[tid + s];
        __syncthreads();
    }
    float inv = 1.0f / red[0];
    __syncthreads();

    int c = tid;                 // 0..255 output channel
    int dir = c >> 7;
    int j = c & 127;
    const bf16_t* hbase = hist + ((size_t)dir * TT * BB + b) * HH + j;
    float acc = 0.f;
    int t = 0;
    for (; t + 4 <= len; t += 4) {
        acc += alpha[t + 0] * (float)hbase[(size_t)(t + 0) * BB * HH];
        acc += alpha[t + 1] * (float)hbase[(size_t)(t + 1) * BB * HH];
        acc += alpha[t + 2] * (float)hbase[(size_t)(t + 2) * BB * HH];
        acc += alpha[t + 3] * (float)hbase[(size_t)(t + 3) * BB * HH];
    }
    for (; t < len; ++t) acc += alpha[t] * (float)hbase[(size_t)t * BB * HH];

    out[(size_t)b * 256 + c] = acc * inv;
}

extern "C" void kernel_launch(void* const* d_in, const int* in_sizes, int n_in,
                              void* d_out, int out_size, void* d_ws, size_t ws_size,
                              hipStream_t stream) {
    const int* X       = (const int*)d_in[0];
    const int* lens    = (const int*)d_in[1];
    const float* emb   = (const float*)d_in[3];
    const float* We2i  = (const float*)d_in[4];
    const float* be2i  = (const float*)d_in[5];
    const float* Wihf  = (const float*)d_in[6];
    const float* Whhf  = (const float*)d_in[7];
    const float* bihf  = (const float*)d_in[8];
    const float* bhhf  = (const float*)d_in[9];
    const float* Wihb  = (const float*)d_in[10];
    const float* Whhb  = (const float*)d_in[11];
    const float* bihb  = (const float*)d_in[12];
    const float* bhhb  = (const float*)d_in[13];
    const float* Wh2o  = (const float*)d_in[14];
    const float* bh2o  = (const float*)d_in[15];
    const float* uw    = (const float*)d_in[16];

    char* ws = (char*)d_ws;
    size_t off = 0;
    bf16_t* xh = (bf16_t*)(ws + off);   off += (size_t)BB * TT * HH * 2;            // 8.4 MB
    bf16_t* gx3 = (bf16_t*)(ws + off);  off += (size_t)8 * TT * 384 * 16 * 2;       // 50.3 MB
    bf16_t* hist = (bf16_t*)(ws + off); off += (size_t)2 * TT * BB * HH * 2;        // 16.8 MB
    float* scores = (float*)(ws + off); off += (size_t)BB * TT * 4;                 // 0.13 MB

    float* out = (float*)d_out;

    k1_xh<<<dim3(BB * TT / 16), dim3(256), 0, stream>>>(X, emb, We2i, be2i, xh);
    k2_gx<<<dim3(TT * 4, 2), dim3(256), 0, stream>>>(xh, Wihf, bihf, Wihb, bihb, gx3);
    k3_gru<<<dim3(4, 2), dim3(512), 0, stream>>>(gx3, Whhf, bhhf, Whhb, bhhb, lens, hist);
    k4_scores<<<dim3(BB * TT / 16), dim3(256), 0, stream>>>(hist, Wh2o, bh2o, uw, scores);
    k5_pool<<<dim3(BB), dim3(256), 0, stream>>>(scores, hist, lens, out);
}

// Round 5
// 595.941 us; speedup vs baseline: 2.1171x; 1.4601x over previous
//
#include <hip/hip_runtime.h>
#include <hip/hip_bf16.h>

// Shapes (fixed by the problem)
#define VV 50000
#define EE 128
#define HH 128
#define OO 128
#define BB 64
#define TT 512

typedef __bf16 bf16_t;
typedef __attribute__((ext_vector_type(8))) __bf16 bf16x8;
typedef __attribute__((ext_vector_type(4))) __bf16 bf16x4;
typedef __attribute__((ext_vector_type(4))) float floatx4;

__device__ __forceinline__ bf16x8 ldb8(const bf16_t* p) {
    return *reinterpret_cast<const bf16x8*>(p);
}

__device__ __forceinline__ float fast_rcp(float x) { return __builtin_amdgcn_rcpf(x); }
// sigmoid/tanh: v_mul + v_exp + v_add + v_rcp (4-5 instr, 2 trans) — NOT the
// IEEE divide sequence (was ~12 instr each without fast-math: R4's VALU bound).
__device__ __forceinline__ float sigmoid_f(float x) {
    return fast_rcp(1.0f + __expf(-x));
}
__device__ __forceinline__ float tanh_f(float x) {
    float e = __expf(2.0f * x);
    return 1.0f - 2.0f * fast_rcp(e + 1.0f);
}

// LDS-only barrier: wait LDS ops, sync — do NOT drain vmcnt (hist stores and
// gx ring-prefetch loads stay in flight across steps).
__device__ __forceinline__ void lds_barrier() {
    asm volatile("s_waitcnt lgkmcnt(0)\n\ts_barrier" ::: "memory");
}

// -------- K0: preconvert weights fp32->bf16 + fold gx bias (bih + bhh for r,z)
__global__ __launch_bounds__(256) void k0_conv(
    const float* __restrict__ emb, const float* __restrict__ we,
    const float* __restrict__ wihf, const float* __restrict__ wihb,
    const float* __restrict__ whhf, const float* __restrict__ whhb,
    const float* __restrict__ wh2o,
    const float* __restrict__ bihf, const float* __restrict__ bhhf,
    const float* __restrict__ bihb, const float* __restrict__ bhhb,
    bf16_t* __restrict__ emb_bf, bf16_t* __restrict__ we_bf,
    bf16_t* __restrict__ wih_bf, bf16_t* __restrict__ whh_bf,
    bf16_t* __restrict__ wh2o_bf, float* __restrict__ gxbias) {
    int tid = blockIdx.x * 256 + threadIdx.x;
    int np = gridDim.x * 256;
    for (int i = tid; i < VV * EE; i += np) emb_bf[i] = (bf16_t)emb[i];
    for (int i = tid; i < HH * EE; i += np) we_bf[i] = (bf16_t)we[i];
    for (int i = tid; i < 384 * HH; i += np) {
        wih_bf[i] = (bf16_t)wihf[i];
        wih_bf[384 * HH + i] = (bf16_t)wihb[i];
        whh_bf[i] = (bf16_t)whhf[i];
        whh_bf[384 * HH + i] = (bf16_t)whhb[i];
    }
    for (int i = tid; i < OO * 256; i += np) wh2o_bf[i] = (bf16_t)wh2o[i];
    if (tid < 768) {
        int dir = tid / 384, n = tid % 384;
        const float* bih = dir ? bihb : bihf;
        const float* bhh = dir ? bhhb : bhhf;
        gxbias[tid] = bih[n] + (n < 256 ? bhh[n] : 0.0f);  // bhh_n stays in K3 (inside r-mul)
    }
}

// -------- K12 (fused K1+K2): per (t, 16-sample group): xh tile in LDS, then
// gx3[dir][g][t][n][b16] = xh @ Wih^T + gxbias  for both dirs.
__global__ __launch_bounds__(256) void k12_gx(const int* __restrict__ X,
                                              const bf16_t* __restrict__ emb_bf,
                                              const bf16_t* __restrict__ we_bf,
                                              const float* __restrict__ be,
                                              const bf16_t* __restrict__ wih_bf,
                                              const float* __restrict__ gxbias,
                                              bf16_t* __restrict__ gx3) {
    int tile = blockIdx.x;           // 0..2047 = t*4 + g
    int t = tile >> 2;
    int g = tile & 3;
    int lane = threadIdx.x & 63;
    int w2 = threadIdx.x >> 6;       // wave 0..3
    int quad = lane >> 4, col = lane & 15;

    __shared__ bf16_t xs[16 * 136];  // xh tile, row-padded

    // stage 1: xh = emb[X] @ We^T + be  (A rows = 16 samples of group g at time t)
    int v = X[(g * 16 + col) * TT + t];
    bf16x8 a[4];
#pragma unroll
    for (int kc = 0; kc < 4; ++kc)
        a[kc] = ldb8(emb_bf + (size_t)v * EE + kc * 32 + quad * 8);

#pragma unroll
    for (int tl = 0; tl < 2; ++tl) {
        int n = 32 * w2 + 16 * tl + col;
        floatx4 acc = {0.f, 0.f, 0.f, 0.f};
#pragma unroll
        for (int kc = 0; kc < 4; ++kc) {
            bf16x8 bw = ldb8(we_bf + (size_t)n * EE + kc * 32 + quad * 8);
            acc = __builtin_amdgcn_mfma_f32_16x16x32_bf16(a[kc], bw, acc, 0, 0, 0);
        }
        float bias = be[n];
#pragma unroll
        for (int r = 0; r < 4; ++r)
            xs[(quad * 4 + r) * 136 + n] = (bf16_t)(acc[r] + bias);
    }
    __syncthreads();

    // stage 2: gx = xh @ Wih^T + gxbias, both dirs (48 n-tiles over 4 waves)
    bf16x8 a2[4];
#pragma unroll
    for (int kc = 0; kc < 4; ++kc)
        a2[kc] = ldb8(xs + col * 136 + kc * 32 + quad * 8);

#pragma unroll
    for (int tl = 0; tl < 12; ++tl) {
        int idx = w2 * 12 + tl;          // 0..47
        int dir = idx >= 24;
        int n = (idx - dir * 24) * 16 + col;   // 0..383
        floatx4 acc = {0.f, 0.f, 0.f, 0.f};
#pragma unroll
        for (int kc = 0; kc < 4; ++kc) {
            bf16x8 bw = ldb8(wih_bf + ((size_t)dir * 384 + n) * HH + kc * 32 + quad * 8);
            acc = __builtin_amdgcn_mfma_f32_16x16x32_bf16(a2[kc], bw, acc, 0, 0, 0);
        }
        float bias = gxbias[dir * 384 + n];
        bf16x4 pack;
#pragma unroll
        for (int r = 0; r < 4; ++r)
            pack[r] = (__bf16)(acc[r] + bias);   // D row r -> local sample quad*4+r
        *reinterpret_cast<bf16x4*>(gx3 + (((size_t)(dir * 4 + g) * TT + t) * 384 + n) * 16 + quad * 4) = pack;
    }
}

// -------- K3: masked GRU recurrence, both directions.
// grid (4 groups of 16 samples, 2 dirs), 512 threads = 8 waves.
// Wave w owns gate columns j = 16w+col for all three gates: r/z/n for the same
// (sample, j) land in the same lane+reg -> in-register gate math.
// Depth-4 register ring prefetch of gx, double-buffered LDS h, one lgkm-only
// barrier per step. hist2 layout [dir*4+g][t][16][128]: per-block contiguous.
#define HPAD 136
#define HBUF (16 * HPAD)
__global__ __launch_bounds__(512) void k3_gru(const bf16_t* __restrict__ gx3,
                                              const bf16_t* __restrict__ whh_bf,
                                              const float* __restrict__ bhh_f,
                                              const float* __restrict__ bhh_b,
                                              const int* __restrict__ lens,
                                              bf16_t* __restrict__ hist2) {
    int g = blockIdx.x;      // sample group: samples 16g..16g+15
    int dir = blockIdx.y;
    const float* bhh = dir ? bhh_b : bhh_f;

    int tid = threadIdx.x;
    int w = tid >> 6;        // wave 0..7
    int lane = tid & 63;
    int quad = lane >> 4, col = lane & 15;
    int j = 16 * w + col;    // owned hidden column

    __shared__ bf16_t hl[2 * HBUF];   // double-buffered h, padded rows
    for (int i = tid; i < 2 * HBUF; i += 512) hl[i] = (bf16_t)0.f;

    int bloc[4], len4[4];
    float h[4] = {0.f, 0.f, 0.f, 0.f};
#pragma unroll
    for (int r = 0; r < 4; ++r) {
        bloc[r] = quad * 4 + r;
        len4[r] = lens[16 * g + bloc[r]];
    }
    int Lmax = 0;
    for (int i = 0; i < 16; ++i) Lmax = max(Lmax, lens[16 * g + i]);

    float bhn = bhh[256 + j];     // only the n-gate hidden bias survives folding

    // Whh B-fragments (pre-converted bf16), resident for all steps
    bf16x8 Bw[3][4];
#pragma unroll
    for (int gate = 0; gate < 3; ++gate)
#pragma unroll
        for (int kc = 0; kc < 4; ++kc)
            Bw[gate][kc] = ldb8(whh_bf + ((size_t)dir * 384 + gate * 128 + j) * HH + kc * 32 + quad * 8);

    const bf16_t* gbase = gx3 + (size_t)(dir * 4 + g) * TT * 6144;
    bf16_t* hb = hist2 + (size_t)(dir * 4 + g) * TT * 2048;
    int loff[3];
#pragma unroll
    for (int gate = 0; gate < 3; ++gate)
        loff[gate] = (gate * 128 + j) * 16 + quad * 4;

    int S4 = (Lmax + 3) & ~3;

    // prefetch ring, depth 4 (raw bf16; convert at consumption)
    bf16x4 ring[4][3];
#pragma unroll
    for (int u = 0; u < 4; ++u) {
        int tr = dir ? (Lmax - 1 - u) : u;
        int t = min(max(tr, 0), Lmax - 1);
#pragma unroll
        for (int gate = 0; gate < 3; ++gate)
            ring[u][gate] = *reinterpret_cast<const bf16x4*>(gbase + (size_t)t * 6144 + loff[gate]);
    }
    lds_barrier();   // zero-init visible

    for (int sb = 0; sb < S4; sb += 4) {
#pragma unroll
        for (int u = 0; u < 4; ++u) {
            int s = sb + u;
            int tr = dir ? (Lmax - 1 - s) : s;
            int t = min(max(tr, 0), Lmax - 1);     // clamped for tail steps
            const bf16_t* hc = hl + (s & 1) * HBUF;
            bf16_t* hn = hl + ((s + 1) & 1) * HBUF;

            // consume ring slot u (loads issued 4 steps ago -> long retired)
            float gxc[3][4];
#pragma unroll
            for (int gate = 0; gate < 3; ++gate)
#pragma unroll
                for (int r = 0; r < 4; ++r)
                    gxc[gate][r] = (float)ring[u][gate][r];

            // A fragments from LDS h  (A row m = lane&15 = col)
            bf16x8 a[4];
#pragma unroll
            for (int kc = 0; kc < 4; ++kc)
                a[kc] = ldb8(hc + col * HPAD + kc * 32 + quad * 8);

            // 2 accumulator chains per gate for MFMA ILP
            floatx4 ar0 = {0,0,0,0}, ar1 = {0,0,0,0};
            floatx4 az0 = {0,0,0,0}, az1 = {0,0,0,0};
            floatx4 an0 = {0,0,0,0}, an1 = {0,0,0,0};
            ar0 = __builtin_amdgcn_mfma_f32_16x16x32_bf16(a[0], Bw[0][0], ar0, 0, 0, 0);
            az0 = __builtin_amdgcn_mfma_f32_16x16x32_bf16(a[0], Bw[1][0], az0, 0, 0, 0);
            an0 = __builtin_amdgcn_mfma_f32_16x16x32_bf16(a[0], Bw[2][0], an0, 0, 0, 0);
            ar1 = __builtin_amdgcn_mfma_f32_16x16x32_bf16(a[2], Bw[0][2], ar1, 0, 0, 0);
            az1 = __builtin_amdgcn_mfma_f32_16x16x32_bf16(a[2], Bw[1][2], az1, 0, 0, 0);
            an1 = __builtin_amdgcn_mfma_f32_16x16x32_bf16(a[2], Bw[2][2], an1, 0, 0, 0);
            ar0 = __builtin_amdgcn_mfma_f32_16x16x32_bf16(a[1], Bw[0][1], ar0, 0, 0, 0);
            az0 = __builtin_amdgcn_mfma_f32_16x16x32_bf16(a[1], Bw[1][1], az0, 0, 0, 0);
            an0 = __builtin_amdgcn_mfma_f32_16x16x32_bf16(a[1], Bw[2][1], an0, 0, 0, 0);
            ar1 = __builtin_amdgcn_mfma_f32_16x16x32_bf16(a[3], Bw[0][3], ar1, 0, 0, 0);
            az1 = __builtin_amdgcn_mfma_f32_16x16x32_bf16(a[3], Bw[1][3], az1, 0, 0, 0);
            an1 = __builtin_amdgcn_mfma_f32_16x16x32_bf16(a[3], Bw[2][3], an1, 0, 0, 0);

            // refill ring slot u for step s+4 (in flight for 4 steps)
            {
                int sn = s + 4;
                int trn = dir ? (Lmax - 1 - sn) : sn;
                int tn = min(max(trn, 0), Lmax - 1);
#pragma unroll
                for (int gate = 0; gate < 3; ++gate)
                    ring[u][gate] = *reinterpret_cast<const bf16x4*>(gbase + (size_t)tn * 6144 + loff[gate]);
            }

            // gates + state update (D row = quad*4+reg = local sample, D col = j)
            bool live = (s < Lmax);
            bf16_t* hrow = hb + (size_t)t * 2048 + j;
#pragma unroll
            for (int r = 0; r < 4; ++r) {
                float rg = sigmoid_f(gxc[0][r] + ar0[r] + ar1[r]);
                float zg = sigmoid_f(gxc[1][r] + az0[r] + az1[r]);
                float ng = tanh_f(gxc[2][r] + rg * (an0[r] + an1[r] + bhn));
                float hn_ = ng + zg * (h[r] - ng);
                h[r] = (live && (t < len4[r])) ? hn_ : h[r];
                hn[bloc[r] * HPAD + j] = (bf16_t)h[r];
                hrow[bloc[r] * 128] = (bf16_t)h[r];
            }

            lds_barrier();   // new h visible; old buffer free
        }
    }
}

// -------- K4: Y = tanh(Hout @ W_h2o^T + b), score = sum(Y*u_w) ; scores[b][t] fp32
__global__ __launch_bounds__(256) void k4_scores(const bf16_t* __restrict__ hist2,
                                                 const bf16_t* __restrict__ wh2o_bf,
                                                 const float* __restrict__ bh2o,
                                                 const float* __restrict__ uw,
                                                 float* __restrict__ scores) {
    int tile = blockIdx.x;          // 0..2047 = t*4 + g
    int t = tile >> 2;
    int g = tile & 3;
    int lane = threadIdx.x & 63;
    int w2 = threadIdx.x >> 6;
    int quad = lane >> 4, col = lane & 15;

    // A fragments: sample (g,col) at t; K=256: kc 0..3 from h_f, 4..7 from h_b
    bf16x8 a[8];
#pragma unroll
    for (int kc = 0; kc < 8; ++kc) {
        int dir = kc >> 2;
        a[kc] = ldb8(hist2 + ((size_t)(dir * 4 + g) * TT + t) * 2048 + col * 128 + (kc & 3) * 32 + quad * 8);
    }

    float p4[4] = {0.f, 0.f, 0.f, 0.f};
#pragma unroll
    for (int tl = 0; tl < 2; ++tl) {
        int n = 32 * w2 + 16 * tl + col;
        floatx4 acc = {0.f, 0.f, 0.f, 0.f};
#pragma unroll
        for (int kc = 0; kc < 8; ++kc) {
            bf16x8 bw = ldb8(wh2o_bf + (size_t)n * 256 + kc * 32 + quad * 8);
            acc = __builtin_amdgcn_mfma_f32_16x16x32_bf16(a[kc], bw, acc, 0, 0, 0);
        }
        float bias = bh2o[n];
        float u = uw[n];
#pragma unroll
        for (int r = 0; r < 4; ++r) {
            float y = tanh_f(acc[r] + bias);
            p4[r] += y * u;
        }
    }
    // reduce over the 16 cols of this quad group (rows identical across them)
#pragma unroll
    for (int m = 1; m < 16; m <<= 1)
#pragma unroll
        for (int r = 0; r < 4; ++r)
            p4[r] += __shfl_xor(p4[r], m, 64);

    __shared__ float part[16][4];
    if (col == 0) {
#pragma unroll
        for (int r = 0; r < 4; ++r) part[quad * 4 + r][w2] = p4[r];
    }
    __syncthreads();
    if (threadIdx.x < 16) {
        float s = part[threadIdx.x][0] + part[threadIdx.x][1] +
                  part[threadIdx.x][2] + part[threadIdx.x][3];
        scores[(size_t)(g * 16 + threadIdx.x) * TT + t] = s;
    }
}

// -------- K5: per-sample softmax over valid t + pooled = sum_t alpha[t]*Hout[b][t][:]
__global__ __launch_bounds__(256) void k5_pool(const float* __restrict__ scores,
                                               const bf16_t* __restrict__ hist2,
                                               const int* __restrict__ lens,
                                               float* __restrict__ out) {
    int b = blockIdx.x;
    int g = b >> 4, bl = b & 15;
    int tid = threadIdx.x;
    int len = lens[b];
    __shared__ float alpha[TT];
    __shared__ float red[256];
    const float* srow = scores + (size_t)b * TT;

    float m = -1e30f;
    for (int t = tid; t < len; t += 256) m = fmaxf(m, srow[t]);
    red[tid] = m;
    __syncthreads();
    for (int s = 128; s > 0; s >>= 1) {
        if (tid < s) red[tid] = fmaxf(red[tid], red[tid + s]);
        __syncthreads();
    }
    float mx = red[0];
    __syncthreads();

    float sum = 0.f;
    for (int t = tid; t < TT; t += 256) {
        float e = (t < len) ? __expf(srow[t] - mx) : 0.f;
        alpha[t] = e;
        sum += e;
    }
    red[tid] = sum;
    __syncthreads();
    for (int s = 128; s > 0; s >>= 1) {
        if (tid < s) red[tid] += red[tid + s];
        __syncthreads();
    }
    float inv = fast_rcp(red[0]);
    __syncthreads();

    int c = tid;                 // 0..255 output channel
    int dir = c >> 7;
    int j = c & 127;
    const bf16_t* hbase = hist2 + ((size_t)(dir * 4 + g) * TT) * 2048 + bl * 128 + j;
    float acc = 0.f;
    int t = 0;
    for (; t + 4 <= len; t += 4) {
        acc += alpha[t + 0] * (float)hbase[(size_t)(t + 0) * 2048];
        acc += alpha[t + 1] * (float)hbase[(size_t)(t + 1) * 2048];
        acc += alpha[t + 2] * (float)hbase[(size_t)(t + 2) * 2048];
        acc += alpha[t + 3] * (float)hbase[(size_t)(t + 3) * 2048];
    }
    for (; t < len; ++t) acc += alpha[t] * (float)hbase[(size_t)t * 2048];

    out[(size_t)b * 256 + c] = acc * inv;
}

extern "C" void kernel_launch(void* const* d_in, const int* in_sizes, int n_in,
                              void* d_out, int out_size, void* d_ws, size_t ws_size,
                              hipStream_t stream) {
    const int* X       = (const int*)d_in[0];
    const int* lens    = (const int*)d_in[1];
    const float* emb   = (const float*)d_in[3];
    const float* We2i  = (const float*)d_in[4];
    const float* be2i  = (const float*)d_in[5];
    const float* Wihf  = (const float*)d_in[6];
    const float* Whhf  = (const float*)d_in[7];
    const float* bihf  = (const float*)d_in[8];
    const float* bhhf  = (const float*)d_in[9];
    const float* Wihb  = (const float*)d_in[10];
    const float* Whhb  = (const float*)d_in[11];
    const float* bihb  = (const float*)d_in[12];
    const float* bhhb  = (const float*)d_in[13];
    const float* Wh2o  = (const float*)d_in[14];
    const float* bh2o  = (const float*)d_in[15];
    const float* uw    = (const float*)d_in[16];

    char* ws = (char*)d_ws;
    size_t off = 0;
    bf16_t* emb_bf = (bf16_t*)(ws + off);  off += (size_t)VV * EE * 2;          // 12.8 MB
    bf16_t* we_bf = (bf16_t*)(ws + off);   off += (size_t)HH * EE * 2;          // 32 KB
    bf16_t* wih_bf = (bf16_t*)(ws + off);  off += (size_t)2 * 384 * HH * 2;     // 192 KB
    bf16_t* whh_bf = (bf16_t*)(ws + off);  off += (size_t)2 * 384 * HH * 2;     // 192 KB
    bf16_t* wh2o_bf = (bf16_t*)(ws + off); off += (size_t)OO * 256 * 2;         // 64 KB
    float* gxbias = (float*)(ws + off);    off += 768 * 4;                      // 3 KB
    off = (off + 255) & ~(size_t)255;
    bf16_t* gx3 = (bf16_t*)(ws + off);     off += (size_t)8 * TT * 384 * 16 * 2; // 50.3 MB
    bf16_t* hist2 = (bf16_t*)(ws + off);   off += (size_t)8 * TT * 16 * 128 * 2; // 16.8 MB
    float* scores = (float*)(ws + off);    off += (size_t)BB * TT * 4;           // 0.13 MB

    float* out = (float*)d_out;

    k0_conv<<<dim3(1024), dim3(256), 0, stream>>>(emb, We2i, Wihf, Wihb, Whhf, Whhb,
                                                  Wh2o, bihf, bhhf, bihb, bhhb,
                                                  emb_bf, we_bf, wih_bf, whh_bf, wh2o_bf, gxbias);
    k12_gx<<<dim3(TT * 4), dim3(256), 0, stream>>>(X, emb_bf, we_bf, be2i, wih_bf, gxbias, gx3);
    k3_gru<<<dim3(4, 2), dim3(512), 0, stream>>>(gx3, whh_bf, bhhf, bhhb, lens, hist2);
    k4_scores<<<dim3(TT * 4), dim3(256), 0, stream>>>(hist2, wh2o_bf, bh2o, uw, scores);
    k5_pool<<<dim3(BB), dim3(256), 0, stream>>>(scores, hist2, lens, out);
}

// Round 6
// 517.813 us; speedup vs baseline: 2.4365x; 1.1509x over previous
//
#include <hip/hip_runtime.h>
#include <hip/hip_bf16.h>

// Shapes (fixed by the problem)
#define VV 50000
#define EE 128
#define HH 128
#define OO 128
#define BB 64
#define TT 512

typedef __bf16 bf16_t;
typedef __attribute__((ext_vector_type(8))) __bf16 bf16x8;
typedef __attribute__((ext_vector_type(4))) __bf16 bf16x4;
typedef __attribute__((ext_vector_type(4))) float floatx4;

__device__ __forceinline__ bf16x8 ldb8(const bf16_t* p) {
    return *reinterpret_cast<const bf16x8*>(p);
}

__device__ __forceinline__ float fast_rcp(float x) { return __builtin_amdgcn_rcpf(x); }
__device__ __forceinline__ float sigmoid_f(float x) {
    return fast_rcp(1.0f + __expf(-x));
}
__device__ __forceinline__ float tanh_f(float x) {
    float e = __expf(2.0f * x);
    return 1.0f - 2.0f * fast_rcp(e + 1.0f);
}

// LDS-only barrier: wait LDS ops, sync — do NOT drain vmcnt (hist stores and
// gx ring-prefetch loads stay in flight across steps).
__device__ __forceinline__ void lds_barrier() {
    asm volatile("s_waitcnt lgkmcnt(0)\n\ts_barrier" ::: "memory");
}

// -------- K0: preconvert weights fp32->bf16 + fold gx bias (bih + bhh for r,z)
__global__ __launch_bounds__(256) void k0_conv(
    const float* __restrict__ emb, const float* __restrict__ we,
    const float* __restrict__ wihf, const float* __restrict__ wihb,
    const float* __restrict__ whhf, const float* __restrict__ whhb,
    const float* __restrict__ wh2o,
    const float* __restrict__ bihf, const float* __restrict__ bhhf,
    const float* __restrict__ bihb, const float* __restrict__ bhhb,
    bf16_t* __restrict__ emb_bf, bf16_t* __restrict__ we_bf,
    bf16_t* __restrict__ wih_bf, bf16_t* __restrict__ whh_bf,
    bf16_t* __restrict__ wh2o_bf, float* __restrict__ gxbias) {
    int tid = blockIdx.x * 256 + threadIdx.x;
    int np = gridDim.x * 256;
    for (int i = tid; i < VV * EE; i += np) emb_bf[i] = (bf16_t)emb[i];
    for (int i = tid; i < HH * EE; i += np) we_bf[i] = (bf16_t)we[i];
    for (int i = tid; i < 384 * HH; i += np) {
        wih_bf[i] = (bf16_t)wihf[i];
        wih_bf[384 * HH + i] = (bf16_t)wihb[i];
        whh_bf[i] = (bf16_t)whhf[i];
        whh_bf[384 * HH + i] = (bf16_t)whhb[i];
    }
    for (int i = tid; i < OO * 256; i += np) wh2o_bf[i] = (bf16_t)wh2o[i];
    if (tid < 768) {
        int dir = tid / 384, n = tid % 384;
        const float* bih = dir ? bihb : bihf;
        const float* bhh = dir ? bhhb : bhhf;
        gxbias[tid] = bih[n] + (n < 256 ? bhh[n] : 0.0f);  // bhh_n goes in K3's C-init
    }
}

// -------- K12 (fused K1+K2): per (t, 16-sample tile): xh tile in LDS, then
// gx3[(dir*16+g4)][t][n][4] = xh @ Wih^T + gxbias  for both dirs.
// gx layout is per-(dir, 4-sample group) contiguous = private to one K3 block.
__global__ __launch_bounds__(256) void k12_gx(const int* __restrict__ X,
                                              const bf16_t* __restrict__ emb_bf,
                                              const bf16_t* __restrict__ we_bf,
                                              const float* __restrict__ be,
                                              const bf16_t* __restrict__ wih_bf,
                                              const float* __restrict__ gxbias,
                                              bf16_t* __restrict__ gx3) {
    int tile = blockIdx.x;           // 0..2047 = t*4 + g
    int t = tile >> 2;
    int g = tile & 3;                // 16-sample tile
    int lane = threadIdx.x & 63;
    int w2 = threadIdx.x >> 6;       // wave 0..3
    int quad = lane >> 4, col = lane & 15;

    __shared__ bf16_t xs[16 * 136];  // xh tile, row-padded

    // stage 1: xh = emb[X] @ We^T + be  (A rows = 16 samples of tile g at time t)
    int v = X[(g * 16 + col) * TT + t];
    bf16x8 a[4];
#pragma unroll
    for (int kc = 0; kc < 4; ++kc)
        a[kc] = ldb8(emb_bf + (size_t)v * EE + kc * 32 + quad * 8);

#pragma unroll
    for (int tl = 0; tl < 2; ++tl) {
        int n = 32 * w2 + 16 * tl + col;
        floatx4 acc = {0.f, 0.f, 0.f, 0.f};
#pragma unroll
        for (int kc = 0; kc < 4; ++kc) {
            bf16x8 bw = ldb8(we_bf + (size_t)n * EE + kc * 32 + quad * 8);
            acc = __builtin_amdgcn_mfma_f32_16x16x32_bf16(a[kc], bw, acc, 0, 0, 0);
        }
        float bias = be[n];
#pragma unroll
        for (int r = 0; r < 4; ++r)
            xs[(quad * 4 + r) * 136 + n] = (bf16_t)(acc[r] + bias);
    }
    __syncthreads();

    // stage 2: gx = xh @ Wih^T + gxbias, both dirs (48 n-tiles over 4 waves)
    bf16x8 a2[4];
#pragma unroll
    for (int kc = 0; kc < 4; ++kc)
        a2[kc] = ldb8(xs + col * 136 + kc * 32 + quad * 8);

#pragma unroll
    for (int tl = 0; tl < 12; ++tl) {
        int idx = w2 * 12 + tl;          // 0..47
        int dir = idx >= 24;
        int n = (idx - dir * 24) * 16 + col;   // 0..383
        floatx4 acc = {0.f, 0.f, 0.f, 0.f};
#pragma unroll
        for (int kc = 0; kc < 4; ++kc) {
            bf16x8 bw = ldb8(wih_bf + ((size_t)dir * 384 + n) * HH + kc * 32 + quad * 8);
            acc = __builtin_amdgcn_mfma_f32_16x16x32_bf16(a2[kc], bw, acc, 0, 0, 0);
        }
        float bias = gxbias[dir * 384 + n];
        bf16x4 pack;
#pragma unroll
        for (int r = 0; r < 4; ++r)
            pack[r] = (__bf16)(acc[r] + bias);   // D row r -> sample 16g+quad*4+r
        // 4-sample group g4 = 4g+quad, local sample r
        *reinterpret_cast<bf16x4*>(
            gx3 + (((size_t)(dir * 16 + 4 * g + quad) * TT + t) * 384 + n) * 4) = pack;
    }
}

// -------- K3: masked GRU recurrence, both directions.
// grid (16 groups of 4 samples, 2 dirs) = 32 blocks, 512 threads = 8 waves.
// Wave w owns j = 16w+col for all three gates. With 4 samples, all real C rows
// (0-3) sit in quad-0 lanes; 3 shfl_xor per gate redistribute rows 1-3 to
// quads 1-3 so EVERY lane does exactly ONE gate update (VALU-bound fix).
#define HPAD 136
#define HBUF (16 * HPAD)
__global__ __launch_bounds__(512) void k3_gru(const bf16_t* __restrict__ gx3,
                                              const bf16_t* __restrict__ whh_bf,
                                              const float* __restrict__ bhh_f,
                                              const float* __restrict__ bhh_b,
                                              const int* __restrict__ lens,
                                              bf16_t* __restrict__ hist2) {
    int g16 = blockIdx.x;    // 4-sample group: samples 4*g16 .. 4*g16+3
    int dir = blockIdx.y;
    const float* bhh = dir ? bhh_b : bhh_f;

    int tid = threadIdx.x;
    int w = tid >> 6;        // wave 0..7
    int lane = tid & 63;
    int quad = lane >> 4, col = lane & 15;
    int j = 16 * w + col;    // owned hidden column

    __shared__ bf16_t hl[2 * HBUF];   // double-buffered h; rows 4-15 stay zero
    for (int i = tid; i < 2 * HBUF; i += 512) hl[i] = (bf16_t)0.f;

    int len1 = lens[4 * g16 + quad];      // this lane's sample
    int Lmax = max(max(lens[4 * g16], lens[4 * g16 + 1]),
                   max(lens[4 * g16 + 2], lens[4 * g16 + 3]));

    float bhn = bhh[256 + j];

    // Whh B-fragments (pre-converted bf16), resident for all steps
    bf16x8 Bw[3][4];
#pragma unroll
    for (int gate = 0; gate < 3; ++gate)
#pragma unroll
        for (int kc = 0; kc < 4; ++kc)
            Bw[gate][kc] = ldb8(whh_bf + ((size_t)dir * 384 + gate * 128 + j) * HH + kc * 32 + quad * 8);

    const bf16_t* gbase = gx3 + (size_t)(dir * 16 + g16) * TT * 1536;
    bf16_t* hb = hist2 + (size_t)(dir * 16 + g16) * TT * 512;
    int loff[3];
#pragma unroll
    for (int gate = 0; gate < 3; ++gate)
        loff[gate] = (gate * 128 + j) * 4 + quad;
    int hoff = quad * 128 + j;

    float h = 0.f;
    int S4 = (Lmax + 3) & ~3;
    bool lowquad = (quad & 1) == 0;
    bool lowhalf = (quad & 2) == 0;

    // prefetch ring, depth 4 (raw bf16 scalars; convert at consumption)
    __bf16 ring[4][3];
#pragma unroll
    for (int u = 0; u < 4; ++u) {
        int tr = dir ? (Lmax - 1 - u) : u;
        int t = min(max(tr, 0), Lmax - 1);
#pragma unroll
        for (int gate = 0; gate < 3; ++gate)
            ring[u][gate] = gbase[(size_t)t * 1536 + loff[gate]];
    }
    lds_barrier();   // zero-init visible

    for (int sb = 0; sb < S4; sb += 4) {
#pragma unroll
        for (int u = 0; u < 4; ++u) {
            int s = sb + u;
            int tr = dir ? (Lmax - 1 - s) : s;
            int t = min(max(tr, 0), Lmax - 1);     // clamped for tail steps
            const bf16_t* hc = hl + (s & 1) * HBUF;
            bf16_t* hn = hl + ((s + 1) & 1) * HBUF;

            // consume ring slot u (loads issued 4 steps ago)
            float gx0 = (float)ring[u][0];
            float gx1 = (float)ring[u][1];
            float gx2 = (float)ring[u][2];

            // A fragments from LDS h  (A row m = col; rows 4-15 read zeros)
            bf16x8 a[4];
#pragma unroll
            for (int kc = 0; kc < 4; ++kc)
                a[kc] = ldb8(hc + col * HPAD + kc * 32 + quad * 8);

            // single 4-deep chain per gate; bhn folded into n-gate C-init
            floatx4 cr = {0.f, 0.f, 0.f, 0.f};
            floatx4 cz = {0.f, 0.f, 0.f, 0.f};
            floatx4 cn = {bhn, bhn, bhn, bhn};
#pragma unroll
            for (int kc = 0; kc < 4; ++kc) {
                cr = __builtin_amdgcn_mfma_f32_16x16x32_bf16(a[kc], Bw[0][kc], cr, 0, 0, 0);
                cz = __builtin_amdgcn_mfma_f32_16x16x32_bf16(a[kc], Bw[1][kc], cz, 0, 0, 0);
                cn = __builtin_amdgcn_mfma_f32_16x16x32_bf16(a[kc], Bw[2][kc], cn, 0, 0, 0);
            }

            // refill ring slot u for step s+4
            {
                int sn = s + 4;
                int trn = dir ? (Lmax - 1 - sn) : sn;
                int tn = min(max(trn, 0), Lmax - 1);
#pragma unroll
                for (int gate = 0; gate < 3; ++gate)
                    ring[u][gate] = gbase[(size_t)tn * 1536 + loff[gate]];
            }

            // fold: rows 0-3 live in quad0's c[0..3]; move row q to quad q.
            // quad0 keeps c[0]; quad1 gets c[1] (xor16); quad2 c[2] (xor32);
            // quad3 c[3] (xor48). All lanes execute all shfls (no divergence).
            float r1 = __shfl_xor(cr[1], 16), r2 = __shfl_xor(cr[2], 32), r3 = __shfl_xor(cr[3], 48);
            float z1 = __shfl_xor(cz[1], 16), z2 = __shfl_xor(cz[2], 32), z3 = __shfl_xor(cz[3], 48);
            float n1 = __shfl_xor(cn[1], 16), n2 = __shfl_xor(cn[2], 32), n3 = __shfl_xor(cn[3], 48);
            float aR = lowhalf ? (lowquad ? cr[0] : r1) : (lowquad ? r2 : r3);
            float aZ = lowhalf ? (lowquad ? cz[0] : z1) : (lowquad ? z2 : z3);
            float aN = lowhalf ? (lowquad ? cn[0] : n1) : (lowquad ? n2 : n3);

            // gate math: ONE channel (sample=quad, hidden=j) per lane
            float rg = sigmoid_f(aR + gx0);
            float zg = sigmoid_f(aZ + gx1);
            float ng = tanh_f(gx2 + rg * aN);
            float hnew = ng + zg * (h - ng);
            bool upd = (s < Lmax) && (t < len1);
            h = upd ? hnew : h;
            bf16_t h16 = (bf16_t)h;
            hn[quad * HPAD + j] = h16;            // LDS row = sample
            hb[(size_t)t * 512 + hoff] = h16;     // hist2 per-block region

            lds_barrier();   // new h visible; old buffer free
        }
    }
}

// -------- K4: Y = tanh(Hout @ W_h2o^T + b), score = sum(Y*u_w) ; scores[b][t] fp32
__global__ __launch_bounds__(256) void k4_scores(const bf16_t* __restrict__ hist2,
                                                 const bf16_t* __restrict__ wh2o_bf,
                                                 const float* __restrict__ bh2o,
                                                 const float* __restrict__ uw,
                                                 float* __restrict__ scores) {
    int tile = blockIdx.x;          // 0..2047 = t*4 + g
    int t = tile >> 2;
    int g = tile & 3;               // 16-sample tile = groups 4g..4g+3
    int lane = threadIdx.x & 63;
    int w2 = threadIdx.x >> 6;
    int quad = lane >> 4, col = lane & 15;

    // A fragments: sample (4g + col>>2, col&3) at t; K=256: h_f then h_b
    bf16x8 a[8];
#pragma unroll
    for (int kc = 0; kc < 8; ++kc) {
        int dir = kc >> 2;
        a[kc] = ldb8(hist2 + ((size_t)(dir * 16 + 4 * g + (col >> 2)) * TT + t) * 512
                     + (col & 3) * 128 + (kc & 3) * 32 + quad * 8);
    }

    float p4[4] = {0.f, 0.f, 0.f, 0.f};
#pragma unroll
    for (int tl = 0; tl < 2; ++tl) {
        int n = 32 * w2 + 16 * tl + col;
        floatx4 acc = {0.f, 0.f, 0.f, 0.f};
#pragma unroll
        for (int kc = 0; kc < 8; ++kc) {
            bf16x8 bw = ldb8(wh2o_bf + (size_t)n * 256 + kc * 32 + quad * 8);
            acc = __builtin_amdgcn_mfma_f32_16x16x32_bf16(a[kc], bw, acc, 0, 0, 0);
        }
        float bias = bh2o[n];
        float u = uw[n];
#pragma unroll
        for (int r = 0; r < 4; ++r) {
            float y = tanh_f(acc[r] + bias);
            p4[r] += y * u;
        }
    }
    // reduce over the 16 cols of this quad group (rows identical across them)
#pragma unroll
    for (int m = 1; m < 16; m <<= 1)
#pragma unroll
        for (int r = 0; r < 4; ++r)
            p4[r] += __shfl_xor(p4[r], m, 64);

    __shared__ float part[16][4];
    if (col == 0) {
#pragma unroll
        for (int r = 0; r < 4; ++r) part[quad * 4 + r][w2] = p4[r];
    }
    __syncthreads();
    if (threadIdx.x < 16) {
        float s = part[threadIdx.x][0] + part[threadIdx.x][1] +
                  part[threadIdx.x][2] + part[threadIdx.x][3];
        scores[(size_t)(g * 16 + threadIdx.x) * TT + t] = s;
    }
}

// -------- K5: per-sample softmax over valid t + pooled = sum_t alpha[t]*Hout[b][t][:]
__global__ __launch_bounds__(512) void k5_pool(const float* __restrict__ scores,
                                               const bf16_t* __restrict__ hist2,
                                               const int* __restrict__ lens,
                                               float* __restrict__ out) {
    int b = blockIdx.x;
    int g16 = b >> 2, bl = b & 3;
    int tid = threadIdx.x;
    int len = lens[b];
    __shared__ float alpha[TT];
    __shared__ float red[512];
    const float* srow = scores + (size_t)b * TT;

    float m = -1e30f;
    for (int t = tid; t < len; t += 512) m = fmaxf(m, srow[t]);
    red[tid] = m;
    __syncthreads();
    for (int s = 256; s > 0; s >>= 1) {
        if (tid < s) red[tid] = fmaxf(red[tid], red[tid + s]);
        __syncthreads();
    }
    float mx = red[0];
    __syncthreads();

    float sum = 0.f;
    for (int t = tid; t < TT; t += 512) {
        float e = (t < len) ? __expf(srow[t] - mx) : 0.f;
        alpha[t] = e;
        sum += e;
    }
    red[tid] = sum;
    __syncthreads();
    for (int s = 256; s > 0; s >>= 1) {
        if (tid < s) red[tid] += red[tid + s];
        __syncthreads();
    }
    float inv = fast_rcp(red[0]);
    __syncthreads();

    // 512 threads = 2 t-halves x 256 channels
    int c = tid & 255;           // output channel
    int half = tid >> 8;
    int dir = c >> 7;
    int j = c & 127;
    const bf16_t* hbase = hist2 + (size_t)(dir * 16 + g16) * TT * 512 + bl * 128 + j;
    float acc = 0.f;
    for (int t = half; t < len; t += 2)
        acc += alpha[t] * (float)hbase[(size_t)t * 512];
    red[tid] = acc;
    __syncthreads();
    if (tid < 256)
        out[(size_t)b * 256 + tid] = (red[tid] + red[tid + 256]) * inv;
}

extern "C" void kernel_launch(void* const* d_in, const int* in_sizes, int n_in,
                              void* d_out, int out_size, void* d_ws, size_t ws_size,
                              hipStream_t stream) {
    const int* X       = (const int*)d_in[0];
    const int* lens    = (const int*)d_in[1];
    const float* emb   = (const float*)d_in[3];
    const float* We2i  = (const float*)d_in[4];
    const float* be2i  = (const float*)d_in[5];
    const float* Wihf  = (const float*)d_in[6];
    const float* Whhf  = (const float*)d_in[7];
    const float* bihf  = (const float*)d_in[8];
    const float* bhhf  = (const float*)d_in[9];
    const float* Wihb  = (const float*)d_in[10];
    const float* Whhb  = (const float*)d_in[11];
    const float* bihb  = (const float*)d_in[12];
    const float* bhhb  = (const float*)d_in[13];
    const float* Wh2o  = (const float*)d_in[14];
    const float* bh2o  = (const float*)d_in[15];
    const float* uw    = (const float*)d_in[16];

    char* ws = (char*)d_ws;
    size_t off = 0;
    bf16_t* emb_bf = (bf16_t*)(ws + off);  off += (size_t)VV * EE * 2;          // 12.8 MB
    bf16_t* we_bf = (bf16_t*)(ws + off);   off += (size_t)HH * EE * 2;          // 32 KB
    bf16_t* wih_bf = (bf16_t*)(ws + off);  off += (size_t)2 * 384 * HH * 2;     // 192 KB
    bf16_t* whh_bf = (bf16_t*)(ws + off);  off += (size_t)2 * 384 * HH * 2;     // 192 KB
    bf16_t* wh2o_bf = (bf16_t*)(ws + off); off += (size_t)OO * 256 * 2;         // 64 KB
    float* gxbias = (float*)(ws + off);    off += 768 * 4;                      // 3 KB
    off = (off + 255) & ~(size_t)255;
    bf16_t* gx3 = (bf16_t*)(ws + off);     off += (size_t)32 * TT * 384 * 4 * 2; // 50.3 MB
    bf16_t* hist2 = (bf16_t*)(ws + off);   off += (size_t)32 * TT * 4 * 128 * 2; // 16.8 MB
    float* scores = (float*)(ws + off);    off += (size_t)BB * TT * 4;           // 0.13 MB

    float* out = (float*)d_out;

    k0_conv<<<dim3(1024), dim3(256), 0, stream>>>(emb, We2i, Wihf, Wihb, Whhf, Whhb,
                                                  Wh2o, bihf, bhhf, bihb, bhhb,
                                                  emb_bf, we_bf, wih_bf, whh_bf, wh2o_bf, gxbias);
    k12_gx<<<dim3(TT * 4), dim3(256), 0, stream>>>(X, emb_bf, we_bf, be2i, wih_bf, gxbias, gx3);
    k3_gru<<<dim3(16, 2), dim3(512), 0, stream>>>(gx3, whh_bf, bhhf, bhhb, lens, hist2);
    k4_scores<<<dim3(TT * 4), dim3(256), 0, stream>>>(hist2, wh2o_bf, bh2o, uw, scores);
    k5_pool<<<dim3(BB), dim3(512), 0, stream>>>(scores, hist2, lens, out);
}